// Round 2
// baseline (461.565 us; speedup 1.0000x reference)
//
#include <hip/hip_runtime.h>
#include <hip/hip_bf16.h>

// Problem constants (from reference setup_inputs)
constexpr int B = 128;
constexpr int A = 8732;
constexpr int C = 21;
constexpr int M = 8;

// ---------------------------------------------------------------------------
// K0: zero accumulators
// accf[0]=conf_pos, accf[1]=loc_sum, accf[2]=conf_hard_neg ; npt = n_pos_total
__global__ void k_init(float* accf, int* npt) {
    int t = threadIdx.x;
    if (t < 3) accf[t] = 0.f;
    if (t == 3) *npt = 0;
}

// ---------------------------------------------------------------------------
// K1: per-batch matching. One block per batch row.
__global__ __launch_bounds__(256) void k_match(
    const float* __restrict__ boxes,    // [B,M,4] raw pixel xy
    const int*   __restrict__ labels,   // [B,M]
    const float* __restrict__ anchors,  // [A,4] cxcy
    int*         __restrict__ packed,   // [B,A]  lab | (obj<<8)
    int*         __restrict__ n_pos,    // [B]
    int*         __restrict__ npt)
{
    __shared__ float         s_iou[A];
    __shared__ unsigned char s_obj[A];
    __shared__ float s_pv[M][4];
    __shared__ int   s_pi[M][4];
    __shared__ int   s_force[M];
    __shared__ int   s_c[4];
    __shared__ float s_box[M][4];
    __shared__ int   s_lab[M];

    const int b = blockIdx.x;
    const int t = threadIdx.x;
    const int lane = t & 63;
    const int wv   = t >> 6;

    if (t < M * 4) ((float*)s_box)[t] = boxes[b * M * 4 + t];
    if (t < M)     s_lab[t] = labels[b * M + t];
    __syncthreads();

    // scaled boxes (match reference: boxes / 300.0) + areas
    float bb[M][4], barea[M];
#pragma unroll
    for (int m = 0; m < M; m++) {
        bb[m][0] = s_box[m][0] / 300.f;
        bb[m][1] = s_box[m][1] / 300.f;
        bb[m][2] = s_box[m][2] / 300.f;
        bb[m][3] = s_box[m][3] / 300.f;
        barea[m] = (bb[m][2] - bb[m][0]) * (bb[m][3] - bb[m][1]);
    }

    float bestv[M];
    int   besti[M];
#pragma unroll
    for (int m = 0; m < M; m++) { bestv[m] = -1.f; besti[m] = 0; }

    const float4* anch4 = (const float4*)anchors;
    for (int a = t; a < A; a += 256) {
        float4 an = anch4[a];
        float ax1 = an.x - an.z / 2.0f, ay1 = an.y - an.w / 2.0f;
        float ax2 = an.x + an.z / 2.0f, ay2 = an.y + an.w / 2.0f;
        float aarea = (ax2 - ax1) * (ay2 - ay1);

        float bmax = -1.f; int bm = 0;
#pragma unroll
        for (int m = 0; m < M; m++) {
            float lx = fmaxf(bb[m][0], ax1), ly = fmaxf(bb[m][1], ay1);
            float rx = fminf(bb[m][2], ax2), ry = fminf(bb[m][3], ay2);
            float iw = fmaxf(rx - lx, 0.f), ih = fmaxf(ry - ly, 0.f);
            float inter = iw * ih;
            float iou = inter / (barea[m] + aarea - inter);
            if (iou > bmax) { bmax = iou; bm = m; }               // first-max over m
            if (iou > bestv[m]) { bestv[m] = iou; besti[m] = a; } // first-max over a (ascending)
        }
        s_iou[a] = bmax;
        s_obj[a] = (unsigned char)bm;
    }

    // per-object argmax: wave shuffle reduce (first-max = smallest index on tie)
#pragma unroll
    for (int m = 0; m < M; m++) {
        float v = bestv[m]; int i = besti[m];
        for (int off = 32; off > 0; off >>= 1) {
            float ov = __shfl_down(v, off);
            int   oi = __shfl_down(i, off);
            if (ov > v || (ov == v && oi < i)) { v = ov; i = oi; }
        }
        if (lane == 0) { s_pv[m][wv] = v; s_pi[m][wv] = i; }
    }
    __syncthreads();

    if (t < M) {
        float bv = -1.f; int bi = 0x7fffffff;
#pragma unroll
        for (int w = 0; w < 4; w++) {
            float v = s_pv[t][w]; int i = s_pi[t][w];
            if (v > bv || (v == bv && i < bi)) { bv = v; bi = i; }
        }
        s_force[t] = bi;
    }
    __syncthreads();

    // numpy fancy-assign semantics: last object wins on duplicate anchors
    if (t == 0) {
        for (int m = 0; m < M; m++) {
            int a = s_force[m];
            s_obj[a] = (unsigned char)m;
            s_iou[a] = 1.0f;
        }
    }
    __syncthreads();

    int cnt = 0;
    for (int a = t; a < A; a += 256) {
        int obj = s_obj[a];
        int lab = s_lab[obj];
        if (s_iou[a] < 0.5f) lab = 0;
        packed[(size_t)b * A + a] = lab | (obj << 8);
        if (lab != 0) cnt++;
    }
    for (int off = 32; off > 0; off >>= 1) cnt += __shfl_down(cnt, off);
    if (lane == 0) s_c[wv] = cnt;
    __syncthreads();
    if (t == 0) {
        int c0 = s_c[0] + s_c[1] + s_c[2] + s_c[3];
        n_pos[b] = c0;
        atomicAdd(npt, c0);
    }
}

// ---------------------------------------------------------------------------
// K2: per-anchor cross-entropy + positive-anchor loc L1.
// 128 threads/block, 128 anchors/block, scores staged in LDS via float4.
__global__ __launch_bounds__(128) void k_ce(
    const float* __restrict__ plocs,    // [B,A,4]
    const float* __restrict__ pscores,  // [B,A,C]
    const float* __restrict__ boxes,    // [B,M,4] raw pixel xy
    const float* __restrict__ anchors,  // [A,4]
    int*         __restrict__ buf,      // in: packed, out: ce_neg bits
    float*       __restrict__ accf)
{
    constexpr int AB = 128;             // anchors per block
    constexpr int NV4 = AB * C / 4;     // 672 float4
    __shared__ float s_sc[AB * C];      // 10752 B, block base is 16B-aligned

    const int t    = threadIdx.x;
    const int base = blockIdx.x * AB;   // flat (b*A + a) base; grid exact

    const float4* src = (const float4*)(pscores + (size_t)base * C);
    float4*       dst = (float4*)s_sc;
    for (int i = t; i < NV4; i += AB) dst[i] = src[i];
    __syncthreads();

    const int idx = base + t;
    const int pk  = buf[idx];
    const int lab = pk & 255;
    const int obj = pk >> 8;

    const float* row = s_sc + t * C;    // stride 21 (odd) -> conflict-free
    float v[C];
    float mx = -1e30f;
#pragma unroll
    for (int c = 0; c < C; c++) { v[c] = row[c]; mx = fmaxf(mx, v[c]); }
    float sum = 0.f, slab = 0.f;
#pragma unroll
    for (int c = 0; c < C; c++) {
        sum += __expf(v[c] - mx);
        if (c == lab) slab = v[c];
    }
    float ce = mx + __logf(sum) - slab;
    ce = fmaxf(ce, 0.f);

    float l_pos = 0.f, l_loc = 0.f;
    float cn = ce;
    if (lab != 0) {
        cn = 0.f;
        l_pos = ce;
        int b = idx / A;
        int a = idx - b * A;
        const float* bx = boxes + ((size_t)b * M + obj) * 4;
        const float* an = anchors + (size_t)a * 4;
        // reference quirk: raw pixel xy boxes fed into cxcy_to_gcxgcy
        float dx = (bx[0] - an[0]) / (an[2] / 10.f);
        float dy = (bx[1] - an[1]) / (an[3] / 10.f);
        float dw = logf(bx[2] / an[2]) * 5.f;
        float dh = logf(bx[3] / an[3]) * 5.f;
        const float* p = plocs + (size_t)idx * 4;
        l_loc = fabsf(p[0] - dx) + fabsf(p[1] - dy) +
                fabsf(p[2] - dw) + fabsf(p[3] - dh);
    }
    ((float*)buf)[idx] = cn;

    // wave reduce; positives are rare so atomics are rare
    for (int off = 32; off > 0; off >>= 1) {
        l_pos += __shfl_down(l_pos, off);
        l_loc += __shfl_down(l_loc, off);
    }
    if ((t & 63) == 0 && (l_pos != 0.f || l_loc != 0.f)) {
        atomicAdd(&accf[0], l_pos);
        atomicAdd(&accf[1], l_loc);
    }
}

// ---------------------------------------------------------------------------
// K3: per-row sum of top-(3*n_pos[b]) of ce_neg via radix select.
// Exact even with ties: sum = sum(v>t) + (K - cnt_gt) * t.
__global__ __launch_bounds__(256) void k_topk(
    const float* __restrict__ ce_neg,   // [B,A] (aliased buf)
    const int*   __restrict__ n_pos,    // [B]
    float*       __restrict__ accf)     // accf[2] += row topK sum
{
    __shared__ unsigned int vals[A];
    __shared__ unsigned int hist[256];  // histogram, then in-place suffix-scan
    __shared__ unsigned int s_prefix, s_krem;
    __shared__ float        rs[4];
    __shared__ unsigned int rc[4];

    const int b = blockIdx.x;
    const int t = threadIdx.x;
    const int lane = t & 63;
    const int wv   = t >> 6;
    const int K = 3 * n_pos[b];
    const float* row = ce_neg + (size_t)b * A;

    {   // coalesced uint4 load (A = 4*2183, row base 16B-aligned)
        const uint4* r4 = (const uint4*)row;
        uint4* v4 = (uint4*)vals;
        for (int i = t; i < A / 4; i += 256) v4[i] = r4[i];
    }
    if (t == 0) { s_prefix = 0u; s_krem = (unsigned)K; }
    __syncthreads();

    if (K <= 0) return;  // uniform branch

    if (K >= A) {        // uniform branch: sum the whole row
        float s = 0.f;
        for (int i = t; i < A; i += 256) s += __uint_as_float(vals[i]);
        for (int off = 32; off > 0; off >>= 1) s += __shfl_down(s, off);
        if (lane == 0) rs[wv] = s;
        __syncthreads();
        if (t == 0) atomicAdd(&accf[2], rs[0] + rs[1] + rs[2] + rs[3]);
        return;
    }

    for (int pass = 0; pass < 4; pass++) {
        const int shift = 24 - 8 * pass;
        const unsigned pref = s_prefix;
        const unsigned krem = s_krem;
        hist[t] = 0u;
        __syncthreads();
        for (int i = t; i < A; i += 256) {
            unsigned int v = vals[i];
            if (pass == 0 || (v >> (shift + 8)) == pref)
                atomicAdd(&hist[(v >> shift) & 255u], 1u);
        }
        __syncthreads();
        // in-place suffix scan: hist[t] := sum(hist[t..255])
        for (int off = 1; off < 256; off <<= 1) {
            unsigned add = (t + off < 256) ? hist[t + off] : 0u;
            __syncthreads();
            hist[t] += add;
            __syncthreads();
        }
        unsigned ssT = hist[t];
        unsigned ssN = (t < 255) ? hist[t + 1] : 0u;
        if (ssT >= krem && ssN < krem) {    // exactly one thread
            s_prefix = (pref << 8) | (unsigned)t;
            s_krem   = krem - ssN;
        }
        __syncthreads();
    }

    const unsigned int tb = s_prefix;  // bits of the K-th largest value
    float sg = 0.f; unsigned int cg = 0;
    for (int i = t; i < A; i += 256) {
        unsigned int v = vals[i];
        if (v > tb) { sg += __uint_as_float(v); cg++; }
    }
    for (int off = 32; off > 0; off >>= 1) {
        sg += __shfl_down(sg, off);
        cg += __shfl_down(cg, off);
    }
    if (lane == 0) { rs[wv] = sg; rc[wv] = cg; }
    __syncthreads();
    if (t == 0) {
        float tv = __uint_as_float(tb);
        float tot = rs[0] + rs[1] + rs[2] + rs[3];
        unsigned cnt = rc[0] + rc[1] + rc[2] + rc[3];
        atomicAdd(&accf[2], tot + (float)(K - (int)cnt) * tv);
    }
}

// ---------------------------------------------------------------------------
// K4: final scalar
__global__ void k_final(const float* __restrict__ accf,
                        const int* __restrict__ npt,
                        float* __restrict__ out)
{
    float n = (float)(*npt);
    float conf_loss = (accf[2] + accf[0]) / n;
    float loc_loss  = accf[1] / (n * 4.f);
    out[0] = conf_loss + loc_loss;
}

// ---------------------------------------------------------------------------
extern "C" void kernel_launch(void* const* d_in, const int* in_sizes, int n_in,
                              void* d_out, int out_size, void* d_ws, size_t ws_size,
                              hipStream_t stream)
{
    const float* plocs   = (const float*)d_in[0];  // [B,A,4]
    const float* pscores = (const float*)d_in[1];  // [B,A,C]
    const float* boxes   = (const float*)d_in[2];  // [B,M,4]
    const int*   labels  = (const int*)d_in[3];    // [B,M]
    const float* anchors = (const float*)d_in[4];  // [A,4]
    float*       out     = (float*)d_out;

    // workspace layout (4-byte elements):
    // [0..2] accf, [3] n_pos_total, [8..8+B) n_pos, [8+B ..) packed/ce_neg [B*A]
    float* accf  = (float*)d_ws;
    int*   npt   = (int*)d_ws + 3;
    int*   n_pos = (int*)d_ws + 8;
    int*   buf   = (int*)d_ws + 8 + B;

    k_init<<<1, 64, 0, stream>>>(accf, npt);
    k_match<<<B, 256, 0, stream>>>(boxes, labels, anchors, buf, n_pos, npt);
    k_ce<<<(B * A) / 128, 128, 0, stream>>>(plocs, pscores, boxes, anchors, buf, accf);
    k_topk<<<B, 256, 0, stream>>>((const float*)buf, n_pos, accf);
    k_final<<<1, 1, 0, stream>>>(accf, npt, out);
}

// Round 3
// 287.755 us; speedup vs baseline: 1.6040x; 1.6040x over previous
//
#include <hip/hip_runtime.h>
#include <hip/hip_bf16.h>

// Problem constants (from reference setup_inputs)
constexpr int B = 128;
constexpr int A = 8732;
constexpr int C = 21;
constexpr int M = 8;

// ---------------------------------------------------------------------------
// K0: zero accumulators
// accf[0]=conf_pos, accf[1]=loc_sum, accf[2]=conf_hard_neg ; npt = n_pos_total
__global__ void k_init(float* accf, int* npt) {
    int t = threadIdx.x;
    if (t < 3) accf[t] = 0.f;
    if (t == 3) *npt = 0;
}

// ---------------------------------------------------------------------------
// K1: per-batch matching. One block (1024 threads) per batch row.
__global__ __launch_bounds__(1024) void k_match(
    const float* __restrict__ boxes,    // [B,M,4] raw pixel xy
    const int*   __restrict__ labels,   // [B,M]
    const float* __restrict__ anchors,  // [A,4] cxcy
    int*         __restrict__ packed,   // [B,A]  lab | (obj<<8)
    int*         __restrict__ n_pos,    // [B]
    int*         __restrict__ npt)
{
    __shared__ float         s_iou[A];
    __shared__ unsigned char s_obj[A];
    __shared__ float s_pv[M][16];
    __shared__ int   s_pi[M][16];
    __shared__ int   s_force[M];
    __shared__ int   s_c[16];
    __shared__ float s_box[M][4];
    __shared__ int   s_lab[M];

    const int b = blockIdx.x;
    const int t = threadIdx.x;
    const int lane = t & 63;
    const int wv   = t >> 6;          // 0..15

    if (t < M * 4) ((float*)s_box)[t] = boxes[b * M * 4 + t];
    if (t < M)     s_lab[t] = labels[b * M + t];
    __syncthreads();

    // scaled boxes (match reference: boxes / 300.0) + areas
    float bb[M][4], barea[M];
#pragma unroll
    for (int m = 0; m < M; m++) {
        bb[m][0] = s_box[m][0] / 300.f;
        bb[m][1] = s_box[m][1] / 300.f;
        bb[m][2] = s_box[m][2] / 300.f;
        bb[m][3] = s_box[m][3] / 300.f;
        barea[m] = (bb[m][2] - bb[m][0]) * (bb[m][3] - bb[m][1]);
    }

    float bestv[M];
    int   besti[M];
#pragma unroll
    for (int m = 0; m < M; m++) { bestv[m] = -1.f; besti[m] = 0; }

    const float4* anch4 = (const float4*)anchors;
    for (int a = t; a < A; a += 1024) {
        float4 an = anch4[a];
        float ax1 = an.x - an.z / 2.0f, ay1 = an.y - an.w / 2.0f;
        float ax2 = an.x + an.z / 2.0f, ay2 = an.y + an.w / 2.0f;
        float aarea = (ax2 - ax1) * (ay2 - ay1);

        float bmax = -1.f; int bm = 0;
#pragma unroll
        for (int m = 0; m < M; m++) {
            float lx = fmaxf(bb[m][0], ax1), ly = fmaxf(bb[m][1], ay1);
            float rx = fminf(bb[m][2], ax2), ry = fminf(bb[m][3], ay2);
            float iw = fmaxf(rx - lx, 0.f), ih = fmaxf(ry - ly, 0.f);
            float inter = iw * ih;
            float iou = inter / (barea[m] + aarea - inter);
            if (iou > bmax) { bmax = iou; bm = m; }               // first-max over m
            if (iou > bestv[m]) { bestv[m] = iou; besti[m] = a; } // first-max over a (ascending)
        }
        s_iou[a] = bmax;
        s_obj[a] = (unsigned char)bm;
    }

    // per-object argmax: wave shuffle reduce (tie-break: smaller anchor index)
#pragma unroll
    for (int m = 0; m < M; m++) {
        float v = bestv[m]; int i = besti[m];
        for (int off = 32; off > 0; off >>= 1) {
            float ov = __shfl_down(v, off);
            int   oi = __shfl_down(i, off);
            if (ov > v || (ov == v && oi < i)) { v = ov; i = oi; }
        }
        if (lane == 0) { s_pv[m][wv] = v; s_pi[m][wv] = i; }
    }
    __syncthreads();

    if (t < M) {
        float bv = -1.f; int bi = 0x7fffffff;
#pragma unroll
        for (int w = 0; w < 16; w++) {
            float v = s_pv[t][w]; int i = s_pi[t][w];
            if (v > bv || (v == bv && i < bi)) { bv = v; bi = i; }
        }
        s_force[t] = bi;
    }
    __syncthreads();

    // numpy fancy-assign semantics: last object wins on duplicate anchors
    if (t == 0) {
        for (int m = 0; m < M; m++) {
            int a = s_force[m];
            s_obj[a] = (unsigned char)m;
            s_iou[a] = 1.0f;
        }
    }
    __syncthreads();

    int cnt = 0;
    for (int a = t; a < A; a += 1024) {
        int obj = s_obj[a];
        int lab = s_lab[obj];
        if (s_iou[a] < 0.5f) lab = 0;
        packed[(size_t)b * A + a] = lab | (obj << 8);
        if (lab != 0) cnt++;
    }
    for (int off = 32; off > 0; off >>= 1) cnt += __shfl_down(cnt, off);
    if (lane == 0) s_c[wv] = cnt;
    __syncthreads();
    if (t == 0) {
        int c0 = 0;
#pragma unroll
        for (int w = 0; w < 16; w++) c0 += s_c[w];
        n_pos[b] = c0;
        atomicAdd(npt, c0);
    }
}

// ---------------------------------------------------------------------------
// K2: per-anchor CE + positive loc L1. One thread per 4 consecutive anchors:
// 84 floats = 21 aligned float4 loads (4x bytes per memory instruction vs
// scalar). A % 4 == 0, so a quad never crosses a batch row.
__global__ __launch_bounds__(256) void k_ce(
    const float* __restrict__ plocs,    // [B,A,4]
    const float* __restrict__ pscores,  // [B,A,C]
    const float* __restrict__ boxes,    // [B,M,4] raw pixel xy
    const float* __restrict__ anchors,  // [A,4]
    int*         __restrict__ buf,      // in: packed, out: ce_neg bits
    float*       __restrict__ accf)
{
    constexpr int NQ = B * A / 4;       // 279424 quads
    const int i4 = blockIdx.x * 256 + threadIdx.x;
    float l_pos = 0.f, l_loc = 0.f;

    if (i4 < NQ) {
        const int base = i4 * 4;        // flat anchor index of quad start
        const float4* s4 = (const float4*)(pscores + (size_t)base * C);
        float4 v[21];
#pragma unroll
        for (int i = 0; i < 21; i++) v[i] = s4[i];   // 336 B contiguous
        const float* f = (const float*)v;            // 84 floats

        int4 pk4 = ((const int4*)buf)[i4];
        const int pks[4] = {pk4.x, pk4.y, pk4.z, pk4.w};

        const int b = base / A;
        const int a0 = base - b * A;

        float4 cn4;
        float* cn = (float*)&cn4;
#pragma unroll
        for (int j = 0; j < 4; j++) {
            const float* row = f + j * C;
            const int lab = pks[j] & 255;
            const int obj = pks[j] >> 8;

            float mx = row[0];
#pragma unroll
            for (int c = 1; c < C; c++) mx = fmaxf(mx, row[c]);
            float sum = 0.f, slab = 0.f;
#pragma unroll
            for (int c = 0; c < C; c++) {
                sum += __expf(row[c] - mx);
                if (c == lab) slab = row[c];
            }
            float ce = mx + __logf(sum) - slab;

            cn[j] = ce;
            if (lab != 0) {
                cn[j] = 0.f;
                l_pos += ce;
                const float* bx = boxes + ((size_t)b * M + obj) * 4;
                const float* an = anchors + (size_t)(a0 + j) * 4;
                // reference quirk: raw pixel xy boxes fed into cxcy_to_gcxgcy
                float dx = (bx[0] - an[0]) / (an[2] / 10.f);
                float dy = (bx[1] - an[1]) / (an[3] / 10.f);
                float dw = logf(bx[2] / an[2]) * 5.f;
                float dh = logf(bx[3] / an[3]) * 5.f;
                float4 p = ((const float4*)plocs)[base + j];
                l_loc += fabsf(p.x - dx) + fabsf(p.y - dy) +
                         fabsf(p.z - dw) + fabsf(p.w - dh);
            }
        }
        ((float4*)buf)[i4] = cn4;
    }

    // wave reduce; positives are rare so atomics are rare
    for (int off = 32; off > 0; off >>= 1) {
        l_pos += __shfl_down(l_pos, off);
        l_loc += __shfl_down(l_loc, off);
    }
    if ((threadIdx.x & 63) == 0 && (l_pos != 0.f || l_loc != 0.f)) {
        atomicAdd(&accf[0], l_pos);
        atomicAdd(&accf[1], l_loc);
    }
}

// ---------------------------------------------------------------------------
// K3: per-row sum of top-(3*n_pos[b]) of ce_neg via radix select.
// Exact even with ties: sum = sum(v>t) + (K - cnt_gt) * t.
__global__ __launch_bounds__(1024) void k_topk(
    const float* __restrict__ ce_neg,   // [B,A] (aliased buf)
    const int*   __restrict__ n_pos,    // [B]
    float*       __restrict__ accf)     // accf[2] += row topK sum
{
    __shared__ unsigned int vals[A];
    __shared__ unsigned int hist[256];  // histogram, then suffix sums
    __shared__ unsigned int s_prefix, s_krem;
    __shared__ float        rs[16];
    __shared__ unsigned int rc[16];

    const int b = blockIdx.x;
    const int t = threadIdx.x;
    const int lane = t & 63;
    const int wv   = t >> 6;
    const int K = 3 * n_pos[b];
    const float* row = ce_neg + (size_t)b * A;

    {   // coalesced uint4 load (A = 4*2183, row base 16B-aligned)
        const uint4* r4 = (const uint4*)row;
        uint4* v4 = (uint4*)vals;
        for (int i = t; i < A / 4; i += 1024) v4[i] = r4[i];
    }
    if (t == 0) { s_prefix = 0u; s_krem = (unsigned)K; }
    __syncthreads();

    if (K <= 0) return;  // uniform branch

    if (K >= A) {        // uniform branch: sum the whole row
        float s = 0.f;
        for (int i = t; i < A; i += 1024) s += __uint_as_float(vals[i]);
        for (int off = 32; off > 0; off >>= 1) s += __shfl_down(s, off);
        if (lane == 0) rs[wv] = s;
        __syncthreads();
        if (t == 0) {
            float tot = 0.f;
#pragma unroll
            for (int w = 0; w < 16; w++) tot += rs[w];
            atomicAdd(&accf[2], tot);
        }
        return;
    }

    for (int pass = 0; pass < 4; pass++) {
        const int shift = 24 - 8 * pass;
        const unsigned pref = s_prefix;
        const unsigned krem = s_krem;
        if (t < 256) hist[t] = 0u;
        __syncthreads();
        for (int i = t; i < A; i += 1024) {
            unsigned int v = vals[i];
            if (pass == 0 || (v >> (shift + 8)) == pref)
                atomicAdd(&hist[(v >> shift) & 255u], 1u);
        }
        __syncthreads();
        // wave-0 suffix scan of the 256 bins (hist[i] := sum hist[i..255])
        if (t < 64) {
            unsigned h0 = hist[4 * t + 0], h1 = hist[4 * t + 1];
            unsigned h2 = hist[4 * t + 2], h3 = hist[4 * t + 3];
            unsigned s3 = h3, s2 = h2 + s3, s1 = h1 + s2, s0 = h0 + s1;
            unsigned suf = s0;                 // inclusive suffix of lane totals
            for (int off = 1; off < 64; off <<= 1) {
                unsigned o = __shfl_down(suf, off);
                if (t + off < 64) suf += o;
            }
            unsigned above = suf - s0;         // totals of lanes > t
            hist[4 * t + 0] = above + s0;
            hist[4 * t + 1] = above + s1;
            hist[4 * t + 2] = above + s2;
            hist[4 * t + 3] = above + s3;
        }
        __syncthreads();
        if (t < 256) {
            unsigned ssT = hist[t];
            unsigned ssN = (t < 255) ? hist[t + 1] : 0u;
            if (ssT >= krem && ssN < krem) {   // exactly one thread
                s_prefix = (pref << 8) | (unsigned)t;
                s_krem   = krem - ssN;
            }
        }
        __syncthreads();
    }

    const unsigned int tb = s_prefix;  // bits of the K-th largest value
    float sg = 0.f; unsigned int cg = 0;
    for (int i = t; i < A; i += 1024) {
        unsigned int v = vals[i];
        if (v > tb) { sg += __uint_as_float(v); cg++; }
    }
    for (int off = 32; off > 0; off >>= 1) {
        sg += __shfl_down(sg, off);
        cg += __shfl_down(cg, off);
    }
    if (lane == 0) { rs[wv] = sg; rc[wv] = cg; }
    __syncthreads();
    if (t == 0) {
        float tv = __uint_as_float(tb);
        float tot = 0.f; unsigned cnt = 0;
#pragma unroll
        for (int w = 0; w < 16; w++) { tot += rs[w]; cnt += rc[w]; }
        atomicAdd(&accf[2], tot + (float)(K - (int)cnt) * tv);
    }
}

// ---------------------------------------------------------------------------
// K4: final scalar
__global__ void k_final(const float* __restrict__ accf,
                        const int* __restrict__ npt,
                        float* __restrict__ out)
{
    float n = (float)(*npt);
    float conf_loss = (accf[2] + accf[0]) / n;
    float loc_loss  = accf[1] / (n * 4.f);
    out[0] = conf_loss + loc_loss;
}

// ---------------------------------------------------------------------------
extern "C" void kernel_launch(void* const* d_in, const int* in_sizes, int n_in,
                              void* d_out, int out_size, void* d_ws, size_t ws_size,
                              hipStream_t stream)
{
    const float* plocs   = (const float*)d_in[0];  // [B,A,4]
    const float* pscores = (const float*)d_in[1];  // [B,A,C]
    const float* boxes   = (const float*)d_in[2];  // [B,M,4]
    const int*   labels  = (const int*)d_in[3];    // [B,M]
    const float* anchors = (const float*)d_in[4];  // [A,4]
    float*       out     = (float*)d_out;

    // workspace layout (4-byte elements):
    // [0..2] accf, [3] n_pos_total, [8..8+B) n_pos, [8+B ..) packed/ce_neg [B*A]
    // buf offset = (8+B)*4 = 544 bytes -> 16B-aligned for int4/float4 access
    float* accf  = (float*)d_ws;
    int*   npt   = (int*)d_ws + 3;
    int*   n_pos = (int*)d_ws + 8;
    int*   buf   = (int*)d_ws + 8 + B;

    k_init<<<1, 64, 0, stream>>>(accf, npt);
    k_match<<<B, 1024, 0, stream>>>(boxes, labels, anchors, buf, n_pos, npt);
    constexpr int NQ = B * A / 4;
    k_ce<<<(NQ + 255) / 256, 256, 0, stream>>>(plocs, pscores, boxes, anchors, buf, accf);
    k_topk<<<B, 1024, 0, stream>>>((const float*)buf, n_pos, accf);
    k_final<<<1, 1, 0, stream>>>(accf, npt, out);
}